// Round 9
// baseline (646.630 us; speedup 1.0000x reference)
//
#include <hip/hip_runtime.h>
#include <hip/hip_bf16.h>

// GlobalAttention: Q_LEN=512, SRC_LEN=2048, B=32, D=1024, F=2048
// Round 9: round-7 skeleton (best so far, 46% MfmaUtil) with the 4
// quadrant-phases MERGED into 2 phases/K-tile: halves barrier count
// (2/tile) and doubles MFMA cluster length (32), holding both B-quadrant
// fragment sets in registers across the tile. Counted vmcnt preserved:
//   phA: vmcnt(2) -> bar -> stage A0',B0' -> RD A0,B0,B1 -> 32 MFMA
//   phB: vmcnt(4) -> bar -> stage B1',A1' -> RD A1      -> 32 MFMA
// (stage order A0,B0,B1,A1 matches consume accounting; never drains to 0
// in steady state). 8-slot XOR swizzle both sides (0 conflicts, 5 rounds).
// Also: 3 split_pair launches merged into one. Numerics = rounds 4-8.

typedef __attribute__((ext_vector_type(8))) short bf16x8;
typedef __attribute__((ext_vector_type(4))) float f32x4;

__device__ __forceinline__ ushort f2bf(float x) {
    unsigned u = __builtin_bit_cast(unsigned, x);
    u += 0x7FFFu + ((u >> 16) & 1u);
    return (ushort)(u >> 16);
}
__device__ __forceinline__ float bf2f(ushort h) {
    unsigned u = (unsigned)h << 16;
    return __builtin_bit_cast(float, u);
}
__device__ __forceinline__ void async16(const ushort* g, ushort* l) {
    __builtin_amdgcn_global_load_lds(
        (const __attribute__((address_space(1))) unsigned int*)g,
        (__attribute__((address_space(3))) unsigned int*)l, 16, 0, 0);
}

#define WAITVM(N) asm volatile("s_waitcnt vmcnt(" #N ")" ::: "memory")
#define BARF() do { __builtin_amdgcn_sched_barrier(0);          \
                    __builtin_amdgcn_s_barrier();               \
                    __builtin_amdgcn_sched_barrier(0);          \
                    asm volatile("" ::: "memory"); } while (0)

// read A-quadrant QM (4 m-frags x 2 k-windows) into av
#define RD_A(QM)                                                              \
  _Pragma("unroll") for (int mi = 0; mi < 4; ++mi)                            \
  _Pragma("unroll") for (int w = 0; w < 2; ++w) {                             \
    const int row_ = (QM)*128 + wmg*64 + mi*16 + lr;                          \
    av[mi][w] = *(const bf16x8*)(bufc + row_*64 + (((w*4+lg)^(lr&7))*8));     \
  }
// read B-quadrant QN (2 n-frags x 2 k-windows) into DST
#define RD_B(QN, DST)                                                         \
  _Pragma("unroll") for (int nj = 0; nj < 2; ++nj)                            \
  _Pragma("unroll") for (int w = 0; w < 2; ++w) {                             \
    const int row_ = (QN)*128 + wnd*32 + nj*16 + lr;                          \
    DST[nj][w] = *(const bf16x8*)(bufc + 16384 + row_*64 + (((w*4+lg)^(lr&7))*8)); \
  }
#define MM(QM, QN, BSRC)                                                      \
  _Pragma("unroll") for (int w = 0; w < 2; ++w)                               \
  _Pragma("unroll") for (int mi = 0; mi < 4; ++mi)                            \
  _Pragma("unroll") for (int nj = 0; nj < 2; ++nj)                            \
    acc[(QM)*4+mi][(QN)*2+nj] = __builtin_amdgcn_mfma_f32_16x16x32_bf16(      \
        av[mi][w], BSRC[nj][w], acc[(QM)*4+mi][(QN)*2+nj], 0, 0, 0);

// ---------------------------------------------------------------------------
// gemm8p: C[m,n] = sum_{seg} sum_k A_s[m*lda+k]*B_s[n*ldb+k]  (NT, K-segments)
// 256x256 tile, BK=64, 512 thr (8 waves: wmg=wid>>2, wnd=wid&3).
// Quadrant (qm,qn): rows qm*128+wmg*64.., cols qn*128+wnd*32.. ; acc[8][4].
// LDS per buffer: A [256][64] at 0, B [256][64] at 16384 elems; 8-slot XOR
// swizzle c16^(row&7) pre-applied on the global stage source and on ds_read.
// OUTMODE: 0=f32, 2=bf16 hi (+lo if non-null)(+bias if non-null), 3=tanh(x+bias)
// ---------------------------------------------------------------------------
template<int OUTMODE>
__global__ __launch_bounds__(512, 2) void gemm8p(
    const ushort* __restrict__ A0s, const ushort* __restrict__ A1s, const ushort* __restrict__ A2s,
    const ushort* __restrict__ B0s, const ushort* __restrict__ B1s, const ushort* __restrict__ B2s,
    long lda, long ldb, int tps, int nseg,
    const float* __restrict__ bias,
    float* __restrict__ Cf, ushort* __restrict__ Chi, ushort* __restrict__ Clo,
    long ldc, long sAb, long sBb, long sCb)
{
    __shared__ ushort lds[2][32768];   // 2 x 64 KiB

    const int t   = threadIdx.x;
    const int l   = t & 63;
    const int wid = t >> 6;
    const int lr  = l & 15;
    const int lg  = l >> 4;
    const int wmg = wid >> 2;   // 0..1  (m position)
    const int wnd = wid & 3;    // 0..3  (n position)

    // XCD-aware bijective block swizzle (all grids have nwg % 8 == 0)
    const int gx = gridDim.x, gy = gridDim.y;
    const int nwg = gx * gy * gridDim.z;
    int w0 = ((int)blockIdx.z * gy + (int)blockIdx.y) * gx + (int)blockIdx.x;
    w0 = (w0 & 7) * (nwg >> 3) + (w0 >> 3);
    const int bx = w0 % gx;
    const int by = (w0 / gx) % gy;
    const int bz = w0 / (gx * gy);

    const long m0 = (long)by * 256;
    const long n0 = (long)bx * 256;

    const ushort* Asg[3] = { A0s + (long)bz * sAb, A1s + (long)bz * sAb, A2s + (long)bz * sAb };
    const ushort* Bsg[3] = { B0s + (long)bz * sBb, B1s + (long)bz * sBb, B2s + (long)bz * sBb };
    const int NTt = nseg * tps;

    // staging: half-tile = 128 rows x 64 k = 2 loads/thread; dest linear,
    // source slot pre-swizzled (t&7)^(rA&7) (row+64 preserves &7).
    const int  rA = t >> 3;
    const long cS = (long)((t & 7) ^ (rA & 7)) * 8;

    auto STAGE = [&](int kt1, bool isB, int half, int destoff) {
        int s2 = (kt1 >= tps) + (kt1 >= 2 * tps);
        long ko = (long)(kt1 - s2 * tps) * 64;
        const ushort* base = isB ? Bsg[s2] : Asg[s2];
        long ld = isB ? ldb : lda;
        long rb = isB ? n0 : m0;
        const ushort* src = base + (rb + half * 128 + rA) * ld + ko + cS;
        ushort* d = &lds[kt1 & 1][destoff + t * 8];
        async16(src, d);
        async16(src + 64 * ld, d + 4096);
    };

    const f32x4 zero = {0.f, 0.f, 0.f, 0.f};
    f32x4 acc[8][4];
#pragma unroll
    for (int i = 0; i < 8; ++i)
#pragma unroll
        for (int j = 0; j < 4; ++j) acc[i][j] = zero;

    // prologue: tile 0, stage order A0,B0,B1,A1 (matches consume accounting)
    STAGE(0, false, 0, 0);
    STAGE(0, true,  0, 16384);
    STAGE(0, true,  1, 24576);
    STAGE(0, false, 1, 8192);

    bf16x8 av[4][2], bv0[2][2], bv1[2][2];

    for (int kt = 0; kt < NTt - 1; ++kt) {
        const ushort* bufc = &lds[kt & 1][0];
        // phase A: quadrants (0,0),(0,1). Needs A0,B0,B1 (first 6 of this
        // tile's 8 loads) -> vmcnt(2). Stages next-tile A0,B0.
        WAITVM(2); BARF();
        STAGE(kt + 1, false, 0, 0);
        STAGE(kt + 1, true,  0, 16384);
        RD_A(0); RD_B(0, bv0); RD_B(1, bv1);
        __builtin_amdgcn_s_setprio(1);
        MM(0, 0, bv0); MM(0, 1, bv1);
        __builtin_amdgcn_s_setprio(0);
        // phase B: quadrants (1,0),(1,1). Needs A1 (last 2 of this tile's
        // loads; 4 newer in flight) -> vmcnt(4). Stages next-tile B1,A1.
        WAITVM(4); BARF();
        STAGE(kt + 1, true,  1, 24576);
        STAGE(kt + 1, false, 1, 8192);
        RD_A(1);
        __builtin_amdgcn_s_setprio(1);
        MM(1, 0, bv0); MM(1, 1, bv1);
        __builtin_amdgcn_s_setprio(0);
    }
    {   // last tile: no staging; graduated drain
        const ushort* bufc = &lds[(NTt - 1) & 1][0];
        WAITVM(2); BARF();
        RD_A(0); RD_B(0, bv0); RD_B(1, bv1);
        __builtin_amdgcn_s_setprio(1);
        MM(0, 0, bv0); MM(0, 1, bv1);
        __builtin_amdgcn_s_setprio(0);
        WAITVM(0); BARF();
        RD_A(1);
        __builtin_amdgcn_s_setprio(1);
        MM(1, 0, bv0); MM(1, 1, bv1);
        __builtin_amdgcn_s_setprio(0);
    }

    // epilogue: 16x16 C/D mapping col = l&15, row = (l>>4)*4 + reg
    float*  Cfb = Cf  ? (Cf  + (long)bz * sCb) : nullptr;
    ushort* Chb = Chi ? (Chi + (long)bz * sCb) : nullptr;
    ushort* Clb = Clo ? (Clo + (long)bz * sCb) : nullptr;
#pragma unroll
    for (int qn = 0; qn < 2; ++qn)
#pragma unroll
    for (int nj = 0; nj < 2; ++nj) {
        long n = n0 + qn * 128 + wnd * 32 + nj * 16 + lr;
        float bvs = 0.f;
        if (OUTMODE == 3) bvs = bias[n];
        if (OUTMODE == 2) { if (bias) bvs = bias[n]; }
#pragma unroll
        for (int qm = 0; qm < 2; ++qm)
#pragma unroll
        for (int mi = 0; mi < 4; ++mi) {
            long mb = m0 + qm * 128 + wmg * 64 + mi * 16 + lg * 4;
#pragma unroll
            for (int r = 0; r < 4; ++r) {
                float x = acc[qm * 4 + mi][qn * 2 + nj][r] + bvs;
                long idx = (mb + r) * ldc + n;
                if (OUTMODE == 3) {
                    Cfb[idx] = tanhf(x);
                } else if (OUTMODE == 2) {
                    ushort h = f2bf(x);
                    Chb[idx] = h;
                    if (Clb) Clb[idx] = f2bf(x - bf2f(h));
                } else {
                    Cfb[idx] = x;
                }
            }
        }
    }
}

// ---------------------------------------------------------------------------
// Merged elementwise f32 -> (hi, lo) bf16 pair over three arrays
// ---------------------------------------------------------------------------
__global__ __launch_bounds__(256) void split3_k(
    const float* __restrict__ a0, ushort* __restrict__ h0, ushort* __restrict__ l0, long n0,
    const float* __restrict__ a1, ushort* __restrict__ h1, ushort* __restrict__ l1, long n1,
    const float* __restrict__ a2, ushort* __restrict__ h2, ushort* __restrict__ l2, long n2)
{
    long i = (long)blockIdx.x * 256 + threadIdx.x;
    const long stride = (long)gridDim.x * 256;
    const long tot = n0 + n1 + n2;
    for (; i < tot; i += stride) {
        const float* src; ushort* hh; ushort* ll; long j = i;
        if (j < n0)           { src = a0; hh = h0; ll = l0; }
        else if (j < n0 + n1) { j -= n0; src = a1; hh = h1; ll = l1; }
        else                  { j -= n0 + n1; src = a2; hh = h2; ll = l2; }
        float4 x = ((const float4*)src)[j];
        ushort4 h, lw;
        h.x = f2bf(x.x); lw.x = f2bf(x.x - bf2f(h.x));
        h.y = f2bf(x.y); lw.y = f2bf(x.y - bf2f(h.y));
        h.z = f2bf(x.z); lw.z = f2bf(x.z - bf2f(h.z));
        h.w = f2bf(x.w); lw.w = f2bf(x.w - bf2f(h.w));
        ((ushort4*)hh)[j] = h;
        ((ushort4*)ll)[j] = lw;
    }
}

// ---------------------------------------------------------------------------
// values [2048][32][1024] f32 -> per batch-group:
//   vhi/vlo [(s*gc+bi)][1024] bf16 pair  (K2 B-operand, NT)
//   vT [bi][1024][2048] bf16             (K4 B-operand, NT)
// ---------------------------------------------------------------------------
__global__ __launch_bounds__(256) void values_conv_k(
    const float* __restrict__ values,
    ushort* __restrict__ vhi, ushort* __restrict__ vlo, ushort* __restrict__ vT,
    int b0, int gc)
{
    __shared__ float tile[64][65];
    const int t  = threadIdx.x;
    const int s0 = blockIdx.x * 64;
    const int v0 = blockIdx.y * 64;
    const int bi = blockIdx.z;
    const int b  = b0 + bi;
#pragma unroll
    for (int i = 0; i < 4; ++i) {
        int c = t + i * 256;
        int r = c >> 4;
        int qq = c & 15;
        float4 x = *(const float4*)(values + ((long)(s0 + r) * 32 + b) * 1024 + v0 + qq * 4);
        ushort4 h, lw;
        h.x = f2bf(x.x); lw.x = f2bf(x.x - bf2f(h.x));
        h.y = f2bf(x.y); lw.y = f2bf(x.y - bf2f(h.y));
        h.z = f2bf(x.z); lw.z = f2bf(x.z - bf2f(h.z));
        h.w = f2bf(x.w); lw.w = f2bf(x.w - bf2f(h.w));
        long rowoff = ((long)(s0 + r) * gc + bi) * 1024 + v0 + qq * 4;
        *(ushort4*)(vhi + rowoff) = h;
        *(ushort4*)(vlo + rowoff) = lw;
        tile[r][qq * 4 + 0] = x.x;
        tile[r][qq * 4 + 1] = x.y;
        tile[r][qq * 4 + 2] = x.z;
        tile[r][qq * 4 + 3] = x.w;
    }
    __syncthreads();
    const int vr = t >> 2;
    const int ss = (t & 3) * 16;
    ushort* dst = vT + ((long)bi * 1024 + v0 + vr) * 2048 + s0 + ss;
#pragma unroll
    for (int j = 0; j < 4; ++j) {
        ushort4 o;
        o.x = f2bf(tile[ss + j * 4 + 0][vr]);
        o.y = f2bf(tile[ss + j * 4 + 1][vr]);
        o.z = f2bf(tile[ss + j * 4 + 2][vr]);
        o.w = f2bf(tile[ss + j * 4 + 3][vr]);
        *(ushort4*)(dst + j * 4) = o;
    }
}

// softmax over 2048-rows, f32 in -> bf16 P out. One 256-thread block per row.
__global__ __launch_bounds__(256) void softmax2048b_k(
    const float* __restrict__ S, ushort* __restrict__ P)
{
    __shared__ float red[4];
    const long row = blockIdx.x;
    const float* p = S + row * 2048 + threadIdx.x * 8;
    float4 a = ((const float4*)p)[0];
    float4 b = ((const float4*)p)[1];

    float m = fmaxf(fmaxf(fmaxf(a.x, a.y), fmaxf(a.z, a.w)),
                    fmaxf(fmaxf(b.x, b.y), fmaxf(b.z, b.w)));
#pragma unroll
    for (int off = 32; off; off >>= 1) m = fmaxf(m, __shfl_xor(m, off));
    int wid = threadIdx.x >> 6;
    if ((threadIdx.x & 63) == 0) red[wid] = m;
    __syncthreads();
    m = fmaxf(fmaxf(red[0], red[1]), fmaxf(red[2], red[3]));
    __syncthreads();

    a.x = __expf(a.x - m); a.y = __expf(a.y - m);
    a.z = __expf(a.z - m); a.w = __expf(a.w - m);
    b.x = __expf(b.x - m); b.y = __expf(b.y - m);
    b.z = __expf(b.z - m); b.w = __expf(b.w - m);

    float s = a.x + a.y + a.z + a.w + b.x + b.y + b.z + b.w;
#pragma unroll
    for (int off = 32; off; off >>= 1) s += __shfl_xor(s, off);
    if ((threadIdx.x & 63) == 0) red[wid] = s;
    __syncthreads();
    s = red[0] + red[1] + red[2] + red[3];
    float inv = 1.0f / s;

    ushort* qp = P + row * 2048 + threadIdx.x * 8;
    ushort4 oA, oB;
    oA.x = f2bf(a.x * inv); oA.y = f2bf(a.y * inv);
    oA.z = f2bf(a.z * inv); oA.w = f2bf(a.w * inv);
    oB.x = f2bf(b.x * inv); oB.y = f2bf(b.y * inv);
    oB.z = f2bf(b.z * inv); oB.w = f2bf(b.w * inv);
    ((ushort4*)qp)[0] = oA;
    ((ushort4*)qp)[1] = oB;
}

// ===========================================================================
// Fallback fp32 path (used only if ws_size is too small)
// ===========================================================================
#define BMF 128
#define BNF 128
#define BKF 16

template<bool NT, int MODE>
__global__ __launch_bounds__(256) void gemm_f32(
    const float* __restrict__ A, const float* __restrict__ A2, int Ksplit,
    const float* __restrict__ Bm, const float* __restrict__ bias,
    float* __restrict__ C,
    long lda, long ldb, long ldc, int K,
    long sAb, long sBb, long sCb)
{
    __shared__ float As[BKF][BMF + 4];
    __shared__ float Bs[BKF][BNF + 4];

    const int bz = blockIdx.z;
    const float* Ab  = A + (long)bz * sAb;
    const float* A2b = A2 ? (A2 + (long)bz * sAb) : nullptr;
    const float* Bb  = Bm + (long)bz * sBb;
    float*       Cb  = C + (long)bz * sCb;

    const int m0 = blockIdx.y * BMF;
    const int n0 = blockIdx.x * BNF;
    const int t  = threadIdx.x;
    const int tx = t & 15;
    const int ty = t >> 4;

    float acc[8][8];
#pragma unroll
    for (int i = 0; i < 8; ++i)
#pragma unroll
        for (int j = 0; j < 8; ++j) acc[i][j] = 0.f;

    for (int k0 = 0; k0 < K; k0 += BKF) {
        const float* Asrc = (A2b && k0 >= Ksplit) ? (A2b - Ksplit) : Ab;
#pragma unroll
        for (int c = 0; c < 2; ++c) {
            int chunk = t + c * 256;
            int row = chunk >> 2;
            int kq  = chunk & 3;
            float4 v = *(const float4*)(Asrc + (long)(m0 + row) * lda + k0 + kq * 4);
            As[kq * 4 + 0][row] = v.x;
            As[kq * 4 + 1][row] = v.y;
            As[kq * 4 + 2][row] = v.z;
            As[kq * 4 + 3][row] = v.w;
        }
        if (NT) {
#pragma unroll
            for (int c = 0; c < 2; ++c) {
                int chunk = t + c * 256;
                int row = chunk >> 2;
                int kq  = chunk & 3;
                float4 v = *(const float4*)(Bb + (long)(n0 + row) * ldb + k0 + kq * 4);
                Bs[kq * 4 + 0][row] = v.x;
                Bs[kq * 4 + 1][row] = v.y;
                Bs[kq * 4 + 2][row] = v.z;
                Bs[kq * 4 + 3][row] = v.w;
            }
        } else {
#pragma unroll
            for (int c = 0; c < 2; ++c) {
                int chunk = t + c * 256;
                int kr = chunk >> 5;
                int vq = chunk & 31;
                float4 v = *(const float4*)(Bb + (long)(k0 + kr) * ldb + n0 + vq * 4);
                *(float4*)&Bs[kr][vq * 4] = v;
            }
        }
        __syncthreads();

#pragma unroll
        for (int k = 0; k < BKF; ++k) {
            float4 a0 = *(const float4*)&As[k][ty * 8];
            float4 a1 = *(const float4*)&As[k][ty * 8 + 4];
            float4 b0 = *(const float4*)&Bs[k][tx * 8];
            float4 b1 = *(const float4*)&Bs[k][tx * 8 + 4];
            float ar[8] = {a0.x, a0.y, a0.z, a0.w, a1.x, a1.y, a1.z, a1.w};
            float br[8] = {b0.x, b0.y, b0.z, b0.w, b1.x, b1.y, b1.z, b1.w};
#pragma unroll
            for (int i = 0; i < 8; ++i)
#pragma unroll
                for (int j = 0; j < 8; ++j)
                    acc[i][j] += ar[i] * br[j];
        }
        __syncthreads();
    }

    float brow[8];
    if (MODE >= 1) {
#pragma unroll
        for (int j = 0; j < 8; ++j) brow[j] = bias[n0 + tx * 8 + j];
    }
#pragma unroll
    for (int i = 0; i < 8; ++i) {
        long row = m0 + ty * 8 + i;
        float v[8];
#pragma unroll
        for (int j = 0; j < 8; ++j) {
            float x = acc[i][j];
            if (MODE >= 1) x += brow[j];
            if (MODE == 2) x = tanhf(x);
            v[j] = x;
        }
        float4* dst = (float4*)&Cb[row * ldc + n0 + tx * 8];
        dst[0] = make_float4(v[0], v[1], v[2], v[3]);
        dst[1] = make_float4(v[4], v[5], v[6], v[7]);
    }
}

__global__ __launch_bounds__(256) void softmax2048(float* __restrict__ S)
{
    __shared__ float red[4];
    float* p = S + (long)blockIdx.x * 2048 + threadIdx.x * 8;
    float4 a = ((float4*)p)[0];
    float4 b = ((float4*)p)[1];

    float m = fmaxf(fmaxf(fmaxf(a.x, a.y), fmaxf(a.z, a.w)),
                    fmaxf(fmaxf(b.x, b.y), fmaxf(b.z, b.w)));
#pragma unroll
    for (int off = 32; off; off >>= 1) m = fmaxf(m, __shfl_xor(m, off));
    int wid = threadIdx.x >> 6;
    if ((threadIdx.x & 63) == 0) red[wid] = m;
    __syncthreads();
    m = fmaxf(fmaxf(red[0], red[1]), fmaxf(red[2], red[3]));
    __syncthreads();

    a.x = __expf(a.x - m); a.y = __expf(a.y - m);
    a.z = __expf(a.z - m); a.w = __expf(a.w - m);
    b.x = __expf(b.x - m); b.y = __expf(b.y - m);
    b.z = __expf(b.z - m); b.w = __expf(b.w - m);

    float s = a.x + a.y + a.z + a.w + b.x + b.y + b.z + b.w;
#pragma unroll
    for (int off = 32; off; off >>= 1) s += __shfl_xor(s, off);
    if ((threadIdx.x & 63) == 0) red[wid] = s;
    __syncthreads();
    s = red[0] + red[1] + red[2] + red[3];
    float inv = 1.0f / s;

    a.x *= inv; a.y *= inv; a.z *= inv; a.w *= inv;
    b.x *= inv; b.y *= inv; b.z *= inv; b.w *= inv;
    ((float4*)p)[0] = a;
    ((float4*)p)[1] = b;
}

// ===========================================================================
extern "C" void kernel_launch(void* const* d_in, const int* in_sizes, int n_in,
                              void* d_out, int out_size, void* d_ws, size_t ws_size,
                              hipStream_t stream)
{
    const float* query  = (const float*)d_in[0];
    const float* values = (const float*)d_in[1];
    const float* W1     = (const float*)d_in[2];
    const float* b1     = (const float*)d_in[3];
    const float* W2     = (const float*)d_in[4];
    const float* b2     = (const float*)d_in[5];
    float* out = (float*)d_out;

    const int Bc = 32, QL = 512, SL = 2048, D = 1024, F = 2048;
    const long R = (long)QL * Bc;   // 16384

    char* p = (char*)d_ws;
    auto take = [&](size_t bytes) -> char* {
        char* r = p;
        p += (bytes + 255) & ~(size_t)255;
        return r;
    };

    ushort* q_hi  = (ushort*)take((size_t)R * D * 2);
    ushort* q_lo  = (ushort*)take((size_t)R * D * 2);
    ushort* w1_hi = (ushort*)take((size_t)D * D * 2);
    ushort* w1_lo = (ushort*)take((size_t)D * D * 2);
    ushort* w2_hi = (ushort*)take((size_t)D * F * 2);
    ushort* w2_lo = (ushort*)take((size_t)D * F * 2);
    ushort* qr_hi = (ushort*)take((size_t)R * D * 2);
    ushort* qr_lo = (ushort*)take((size_t)R * D * 2);
    ushort* at_hi = (ushort*)take((size_t)R * D * 2);
    size_t fixedBytes = (size_t)(p - (char*)d_ws);

    // per batch: vals hi+lo+vT (3 x 4 MB) + scores f32 (4 MB) + P bf16 (2 MB)
    const size_t perBatch = (size_t)SL * D * 2 * 3 + (size_t)QL * SL * 4 + (size_t)QL * SL * 2 + 2048;
    long availB = (long)ws_size - (long)fixedBytes;
    int g = availB > 0 ? (int)(availB / (long)perBatch) : 0;
    if (g > 32) g = 32;

    if (g >= 1) {
        // ----------------------- fast split-bf16 MFMA path -----------------
        ushort* vals_hi = (ushort*)take((size_t)SL * D * 2 * g);
        ushort* vals_lo = (ushort*)take((size_t)SL * D * 2 * g);
        ushort* vT      = (ushort*)take((size_t)SL * D * 2 * g);
        float*  scores  = (float*) take((size_t)QL * SL * 4 * g);
        ushort* P       = (ushort*)take((size_t)QL * SL * 2 * g);

        split3_k<<<2048, 256, 0, stream>>>(
            query, q_hi, q_lo, R * D / 4,
            W1, w1_hi, w1_lo, (long)D * D / 4,
            W2, w2_hi, w2_lo, (long)D * F / 4);

        // K1: qr = query.W1^T + b1  (3-term split segments) -> bf16 pair
        gemm8p<2><<<dim3(D / 256, R / 256, 1), 512, 0, stream>>>(
            q_hi, q_hi, q_lo, w1_hi, w1_lo, w1_hi,
            D, D, 16, 3, b1,
            nullptr, qr_hi, qr_lo,
            D, 0, 0, 0);

        for (int b0 = 0; b0 < Bc; b0 += g) {
            int gc = (Bc - b0 < g) ? (Bc - b0) : g;

            values_conv_k<<<dim3(SL / 64, D / 64, gc), 256, 0, stream>>>(
                values, vals_hi, vals_lo, vT, b0, gc);

            // K2: scores = qr . values  (3-term split segments) -> f32
            gemm8p<0><<<dim3(SL / 256, QL / 256, gc), 512, 0, stream>>>(
                qr_hi + (size_t)b0 * D, qr_hi + (size_t)b0 * D, qr_lo + (size_t)b0 * D,
                vals_hi, vals_lo, vals_hi,
                (long)Bc * D, (long)gc * D, 16, 3, nullptr,
                scores, nullptr, nullptr,
                SL, D, D, (long)QL * SL);

            softmax2048b_k<<<gc * QL, 256, 0, stream>>>(scores, P);

            // K4: att = P . vT  (1-term, K=2048) -> bf16 hi only
            gemm8p<2><<<dim3(D / 256, QL / 256, gc), 512, 0, stream>>>(
                P, P, P, vT, vT, vT,
                SL, SL, 32, 1, nullptr,
                nullptr, at_hi + (size_t)b0 * D, nullptr,
                (long)Bc * D, (long)QL * SL, (long)D * SL, D);
        }

        // K5: out = tanh([att | query] . W2^T + b2)  (1-term, 2 K-segments)
        gemm8p<3><<<dim3(D / 256, R / 256, 1), 512, 0, stream>>>(
            at_hi, q_hi, q_hi, w2_hi, w2_hi + 1024, w2_hi,
            D, F, 16, 2, b2,
            out, nullptr, nullptr,
            D, 0, 0, 0);
        return;
    }

    // ----------------------- fp32 fallback ---------------------------------
    float* qr = (float*)d_ws;
    size_t qrBytes = (size_t)R * D * sizeof(float);
    float* sc = (float*)((char*)d_ws + qrBytes);
    size_t scPerB = (size_t)QL * SL * sizeof(float);

    int grp = 32;
    if (ws_size < qrBytes + 32 * scPerB) {
        size_t avail = ws_size > qrBytes ? ws_size - qrBytes : 0;
        grp = (int)(avail / scPerB);
        if (grp < 1)  grp = 1;
        if (grp > 32) grp = 32;
    }

    {
        dim3 gd(D / BNF, R / BMF, 1);
        gemm_f32<true, 1><<<gd, 256, 0, stream>>>(
            query, nullptr, 1 << 30, W1, b1, qr,
            D, D, D, D, 0, 0, 0);
    }
    for (int b0 = 0; b0 < Bc; b0 += grp) {
        int gg = (Bc - b0 < grp) ? (Bc - b0) : grp;
        {
            dim3 gd(SL / BNF, QL / BMF, gg);
            gemm_f32<true, 0><<<gd, 256, 0, stream>>>(
                qr + (size_t)b0 * D, nullptr, 1 << 30,
                values + (size_t)b0 * D, nullptr, sc,
                (long)Bc * D, (long)Bc * D, SL, D,
                D, D, (long)QL * SL);
        }
        softmax2048<<<gg * QL, 256, 0, stream>>>(sc);
        {
            dim3 gd(D / BNF, QL / BMF, gg);
            gemm_f32<false, 0><<<gd, 256, 0, stream>>>(
                sc, nullptr, 1 << 30,
                values + (size_t)b0 * D, nullptr, qr + (size_t)b0 * D,
                SL, (long)Bc * D, (long)Bc * D, SL,
                (long)QL * SL, D, D);
        }
    }
    {
        dim3 gd(D / BNF, R / BMF, 1);
        gemm_f32<true, 2><<<gd, 256, 0, stream>>>(
            qr, query, D, W2, b2, out,
            D, 2048, D, 2048, 0, 0, 0);
    }
}

// Round 10
// 578.463 us; speedup vs baseline: 1.1178x; 1.1178x over previous
//
#include <hip/hip_runtime.h>
#include <hip/hip_bf16.h>

// GlobalAttention: Q_LEN=512, SRC_LEN=2048, B=32, D=1024, F=2048
// Round 10: precision-format optimization (schedule = round 9, capped ~45%):
//   error budget showed absmax dominated by P/vT bf16 (2^-9) tails, not the
//   score path -> move P, vT, and K2's B operand to fp16 (2^-11):
//   K1: query.W1^T + b1   bf16 3-term (W1 lo would be fp16-subnormal)
//                          -> epilogue writes qr as **fp16 pair**
//   K2: scores = (qr_h + qr_l) . v16   fp16 **2-term** (was 3), f32 out
//   SM: softmax -> P fp16
//   K4: att = P . vT       fp16 1-term -> bf16-hi out
//   K5: tanh([att|q].W2^T) bf16 1-term, 2 K-segments (unchanged)
// Executed GEMM work 446 -> 378 GF; values_conv drops vals_lo stream.

typedef __attribute__((ext_vector_type(8))) short    bf16x8;
typedef __attribute__((ext_vector_type(8))) _Float16 f16x8;
typedef __attribute__((ext_vector_type(4))) float    f32x4;

__device__ __forceinline__ ushort f2bf(float x) {
    unsigned u = __builtin_bit_cast(unsigned, x);
    u += 0x7FFFu + ((u >> 16) & 1u);
    return (ushort)(u >> 16);
}
__device__ __forceinline__ float bf2f(ushort h) {
    unsigned u = (unsigned)h << 16;
    return __builtin_bit_cast(float, u);
}
__device__ __forceinline__ ushort f2h(float x) {
    _Float16 h = (_Float16)x;
    return __builtin_bit_cast(ushort, h);
}
__device__ __forceinline__ float h2f(ushort u) {
    return (float)__builtin_bit_cast(_Float16, u);
}
__device__ __forceinline__ void async16(const ushort* g, ushort* l) {
    __builtin_amdgcn_global_load_lds(
        (const __attribute__((address_space(1))) unsigned int*)g,
        (__attribute__((address_space(3))) unsigned int*)l, 16, 0, 0);
}

template<bool F16>
__device__ __forceinline__ f32x4 mmop(bf16x8 a, bf16x8 b, f32x4 c) {
    if constexpr (F16)
        return __builtin_amdgcn_mfma_f32_16x16x32_f16(
            __builtin_bit_cast(f16x8, a), __builtin_bit_cast(f16x8, b), c, 0, 0, 0);
    else
        return __builtin_amdgcn_mfma_f32_16x16x32_bf16(a, b, c, 0, 0, 0);
}

#define WAITVM(N) asm volatile("s_waitcnt vmcnt(" #N ")" ::: "memory")
#define BARF() do { __builtin_amdgcn_sched_barrier(0);          \
                    __builtin_amdgcn_s_barrier();               \
                    __builtin_amdgcn_sched_barrier(0);          \
                    asm volatile("" ::: "memory"); } while (0)

// read A-quadrant QM (4 m-frags x 2 k-windows) into av
#define RD_A(QM)                                                              \
  _Pragma("unroll") for (int mi = 0; mi < 4; ++mi)                            \
  _Pragma("unroll") for (int w = 0; w < 2; ++w) {                             \
    const int row_ = (QM)*128 + wmg*64 + mi*16 + lr;                          \
    av[mi][w] = *(const bf16x8*)(bufc + row_*64 + (((w*4+lg)^(lr&7))*8));     \
  }
// read B-quadrant QN (2 n-frags x 2 k-windows) into DST
#define RD_B(QN, DST)                                                         \
  _Pragma("unroll") for (int nj = 0; nj < 2; ++nj)                            \
  _Pragma("unroll") for (int w = 0; w < 2; ++w) {                             \
    const int row_ = (QN)*128 + wnd*32 + nj*16 + lr;                          \
    DST[nj][w] = *(const bf16x8*)(bufc + 16384 + row_*64 + (((w*4+lg)^(lr&7))*8)); \
  }
#define MM(QM, QN, BSRC)                                                      \
  _Pragma("unroll") for (int w = 0; w < 2; ++w)                               \
  _Pragma("unroll") for (int mi = 0; mi < 4; ++mi)                            \
  _Pragma("unroll") for (int nj = 0; nj < 2; ++nj)                            \
    acc[(QM)*4+mi][(QN)*2+nj] = mmop<F16>(                                    \
        av[mi][w], BSRC[nj][w], acc[(QM)*4+mi][(QN)*2+nj]);

// ---------------------------------------------------------------------------
// gemm8p: C[m,n] = sum_{seg} sum_k A_s[m*lda+k]*B_s[n*ldb+k]  (NT, K-segments)
// 256x256 tile, BK=64, 512 thr (8 waves: wmg=wid>>2, wnd=wid&3).
// Round-9 2-phase schedule: per K-tile
//   phA: vmcnt(2) -> bar -> stage A0',B0' -> RD A0,B0,B1 -> 32 MFMA
//   phB: vmcnt(4) -> bar -> stage B1',A1' -> RD A1      -> 32 MFMA
// 8-slot XOR swizzle c16^(row&7) both sides (0 conflicts, 6 rounds).
// F16: operand dtype (fp16 vs bf16 MFMA). OUT16: OUTMODE-2 pair dtype.
// OUTMODE: 0=f32, 2=hi(+lo if non-null)(+bias if non-null), 3=tanh(x+bias)
// ---------------------------------------------------------------------------
template<int OUTMODE, bool F16, bool OUT16>
__global__ __launch_bounds__(512, 2) void gemm8p(
    const ushort* __restrict__ A0s, const ushort* __restrict__ A1s, const ushort* __restrict__ A2s,
    const ushort* __restrict__ B0s, const ushort* __restrict__ B1s, const ushort* __restrict__ B2s,
    long lda, long ldb, int tps, int nseg,
    const float* __restrict__ bias,
    float* __restrict__ Cf, ushort* __restrict__ Chi, ushort* __restrict__ Clo,
    long ldc, long sAb, long sBb, long sCb)
{
    __shared__ ushort lds[2][32768];   // 2 x 64 KiB

    const int t   = threadIdx.x;
    const int l   = t & 63;
    const int wid = t >> 6;
    const int lr  = l & 15;
    const int lg  = l >> 4;
    const int wmg = wid >> 2;   // 0..1  (m position)
    const int wnd = wid & 3;    // 0..3  (n position)

    // XCD-aware bijective block swizzle (all grids have nwg % 8 == 0)
    const int gx = gridDim.x, gy = gridDim.y;
    const int nwg = gx * gy * gridDim.z;
    int w0 = ((int)blockIdx.z * gy + (int)blockIdx.y) * gx + (int)blockIdx.x;
    w0 = (w0 & 7) * (nwg >> 3) + (w0 >> 3);
    const int bx = w0 % gx;
    const int by = (w0 / gx) % gy;
    const int bz = w0 / (gx * gy);

    const long m0 = (long)by * 256;
    const long n0 = (long)bx * 256;

    const ushort* Asg[3] = { A0s + (long)bz * sAb, A1s + (long)bz * sAb, A2s + (long)bz * sAb };
    const ushort* Bsg[3] = { B0s + (long)bz * sBb, B1s + (long)bz * sBb, B2s + (long)bz * sBb };
    const int NTt = nseg * tps;

    // staging: half-tile = 128 rows x 64 k = 2 loads/thread; dest linear,
    // source slot pre-swizzled (t&7)^(rA&7) (row+64 preserves &7).
    const int  rA = t >> 3;
    const long cS = (long)((t & 7) ^ (rA & 7)) * 8;

    auto STAGE = [&](int kt1, bool isB, int half, int destoff) {
        int s2 = (kt1 >= tps) + (kt1 >= 2 * tps);
        long ko = (long)(kt1 - s2 * tps) * 64;
        const ushort* base = isB ? Bsg[s2] : Asg[s2];
        long ld = isB ? ldb : lda;
        long rb = isB ? n0 : m0;
        const ushort* src = base + (rb + half * 128 + rA) * ld + ko + cS;
        ushort* d = &lds[kt1 & 1][destoff + t * 8];
        async16(src, d);
        async16(src + 64 * ld, d + 4096);
    };

    const f32x4 zero = {0.f, 0.f, 0.f, 0.f};
    f32x4 acc[8][4];
#pragma unroll
    for (int i = 0; i < 8; ++i)
#pragma unroll
        for (int j = 0; j < 4; ++j) acc[i][j] = zero;

    // prologue: tile 0, stage order A0,B0,B1,A1 (matches consume accounting)
    STAGE(0, false, 0, 0);
    STAGE(0, true,  0, 16384);
    STAGE(0, true,  1, 24576);
    STAGE(0, false, 1, 8192);

    bf16x8 av[4][2], bv0[2][2], bv1[2][2];

    for (int kt = 0; kt < NTt - 1; ++kt) {
        const ushort* bufc = &lds[kt & 1][0];
        // phase A: quadrants (0,0),(0,1). Needs A0,B0,B1 -> vmcnt(2).
        WAITVM(2); BARF();
        STAGE(kt + 1, false, 0, 0);
        STAGE(kt + 1, true,  0, 16384);
        RD_A(0); RD_B(0, bv0); RD_B(1, bv1);
        __builtin_amdgcn_s_setprio(1);
        MM(0, 0, bv0); MM(0, 1, bv1);
        __builtin_amdgcn_s_setprio(0);
        // phase B: quadrants (1,0),(1,1). Needs A1 -> vmcnt(4).
        WAITVM(4); BARF();
        STAGE(kt + 1, true,  1, 24576);
        STAGE(kt + 1, false, 1, 8192);
        RD_A(1);
        __builtin_amdgcn_s_setprio(1);
        MM(1, 0, bv0); MM(1, 1, bv1);
        __builtin_amdgcn_s_setprio(0);
    }
    {   // last tile: no staging; graduated drain
        const ushort* bufc = &lds[(NTt - 1) & 1][0];
        WAITVM(2); BARF();
        RD_A(0); RD_B(0, bv0); RD_B(1, bv1);
        __builtin_amdgcn_s_setprio(1);
        MM(0, 0, bv0); MM(0, 1, bv1);
        __builtin_amdgcn_s_setprio(0);
        WAITVM(0); BARF();
        RD_A(1);
        __builtin_amdgcn_s_setprio(1);
        MM(1, 0, bv0); MM(1, 1, bv1);
        __builtin_amdgcn_s_setprio(0);
    }

    // epilogue: 16x16 C/D mapping col = l&15, row = (l>>4)*4 + reg
    float*  Cfb = Cf  ? (Cf  + (long)bz * sCb) : nullptr;
    ushort* Chb = Chi ? (Chi + (long)bz * sCb) : nullptr;
    ushort* Clb = Clo ? (Clo + (long)bz * sCb) : nullptr;
#pragma unroll
    for (int qn = 0; qn < 2; ++qn)
#pragma unroll
    for (int nj = 0; nj < 2; ++nj) {
        long n = n0 + qn * 128 + wnd * 32 + nj * 16 + lr;
        float bvs = 0.f;
        if (OUTMODE == 3) bvs = bias[n];
        if (OUTMODE == 2) { if (bias) bvs = bias[n]; }
#pragma unroll
        for (int qm = 0; qm < 2; ++qm)
#pragma unroll
        for (int mi = 0; mi < 4; ++mi) {
            long mb = m0 + qm * 128 + wmg * 64 + mi * 16 + lg * 4;
#pragma unroll
            for (int r = 0; r < 4; ++r) {
                float x = acc[qm * 4 + mi][qn * 2 + nj][r] + bvs;
                long idx = (mb + r) * ldc + n;
                if (OUTMODE == 3) {
                    Cfb[idx] = tanhf(x);
                } else if (OUTMODE == 2) {
                    if (OUT16) {
                        ushort h = f2h(x);
                        Chb[idx] = h;
                        if (Clb) Clb[idx] = f2h(x - h2f(h));
                    } else {
                        ushort h = f2bf(x);
                        Chb[idx] = h;
                        if (Clb) Clb[idx] = f2bf(x - bf2f(h));
                    }
                } else {
                    Cfb[idx] = x;
                }
            }
        }
    }
}

// ---------------------------------------------------------------------------
// Merged elementwise f32 -> (hi, lo) bf16 pair over three arrays (lo nullable)
// ---------------------------------------------------------------------------
__global__ __launch_bounds__(256) void split3_k(
    const float* __restrict__ a0, ushort* __restrict__ h0, ushort* __restrict__ l0, long n0,
    const float* __restrict__ a1, ushort* __restrict__ h1, ushort* __restrict__ l1, long n1,
    const float* __restrict__ a2, ushort* __restrict__ h2, ushort* __restrict__ l2, long n2)
{
    long i = (long)blockIdx.x * 256 + threadIdx.x;
    const long stride = (long)gridDim.x * 256;
    const long tot = n0 + n1 + n2;
    for (; i < tot; i += stride) {
        const float* src; ushort* hh; ushort* ll; long j = i;
        if (j < n0)           { src = a0; hh = h0; ll = l0; }
        else if (j < n0 + n1) { j -= n0; src = a1; hh = h1; ll = l1; }
        else                  { j -= n0 + n1; src = a2; hh = h2; ll = l2; }
        float4 x = ((const float4*)src)[j];
        ushort4 h;
        h.x = f2bf(x.x); h.y = f2bf(x.y); h.z = f2bf(x.z); h.w = f2bf(x.w);
        ((ushort4*)hh)[j] = h;
        if (ll) {
            ushort4 lw;
            lw.x = f2bf(x.x - bf2f(h.x));
            lw.y = f2bf(x.y - bf2f(h.y));
            lw.z = f2bf(x.z - bf2f(h.z));
            lw.w = f2bf(x.w - bf2f(h.w));
            ((ushort4*)ll)[j] = lw;
        }
    }
}

// ---------------------------------------------------------------------------
// values [2048][32][1024] f32 -> per batch-group:
//   v16 [(s*gc+bi)][1024] fp16   (K2 B-operand, NT, single precision level)
//   vT  [bi][1024][2048]  fp16   (K4 B-operand, NT)
// ---------------------------------------------------------------------------
__global__ __launch_bounds__(256) void values_conv_k(
    const float* __restrict__ values,
    ushort* __restrict__ v16, ushort* __restrict__ vT,
    int b0, int gc)
{
    __shared__ float tile[64][65];
    const int t  = threadIdx.x;
    const int s0 = blockIdx.x * 64;
    const int v0 = blockIdx.y * 64;
    const int bi = blockIdx.z;
    const int b  = b0 + bi;
#pragma unroll
    for (int i = 0; i < 4; ++i) {
        int c = t + i * 256;
        int r = c >> 4;
        int qq = c & 15;
        float4 x = *(const float4*)(values + ((long)(s0 + r) * 32 + b) * 1024 + v0 + qq * 4);
        ushort4 h;
        h.x = f2h(x.x); h.y = f2h(x.y); h.z = f2h(x.z); h.w = f2h(x.w);
        long rowoff = ((long)(s0 + r) * gc + bi) * 1024 + v0 + qq * 4;
        *(ushort4*)(v16 + rowoff) = h;
        tile[r][qq * 4 + 0] = x.x;
        tile[r][qq * 4 + 1] = x.y;
        tile[r][qq * 4 + 2] = x.z;
        tile[r][qq * 4 + 3] = x.w;
    }
    __syncthreads();
    const int vr = t >> 2;
    const int ss = (t & 3) * 16;
    ushort* dst = vT + ((long)bi * 1024 + v0 + vr) * 2048 + s0 + ss;
#pragma unroll
    for (int j = 0; j < 4; ++j) {
        ushort4 o;
        o.x = f2h(tile[ss + j * 4 + 0][vr]);
        o.y = f2h(tile[ss + j * 4 + 1][vr]);
        o.z = f2h(tile[ss + j * 4 + 2][vr]);
        o.w = f2h(tile[ss + j * 4 + 3][vr]);
        *(ushort4*)(dst + j * 4) = o;
    }
}

// softmax over 2048-rows, f32 in -> fp16 P out. One 256-thread block per row.
__global__ __launch_bounds__(256) void softmax2048b_k(
    const float* __restrict__ S, ushort* __restrict__ P)
{
    __shared__ float red[4];
    const long row = blockIdx.x;
    const float* p = S + row * 2048 + threadIdx.x * 8;
    float4 a = ((const float4*)p)[0];
    float4 b = ((const float4*)p)[1];

    float m = fmaxf(fmaxf(fmaxf(a.x, a.y), fmaxf(a.z, a.w)),
                    fmaxf(fmaxf(b.x, b.y), fmaxf(b.z, b.w)));
#pragma unroll
    for (int off = 32; off; off >>= 1) m = fmaxf(m, __shfl_xor(m, off));
    int wid = threadIdx.x >> 6;
    if ((threadIdx.x & 63) == 0) red[wid] = m;
    __syncthreads();
    m = fmaxf(fmaxf(red[0], red[1]), fmaxf(red[2], red[3]));
    __syncthreads();

    a.x = __expf(a.x - m); a.y = __expf(a.y - m);
    a.z = __expf(a.z - m); a.w = __expf(a.w - m);
    b.x = __expf(b.x - m); b.y = __expf(b.y - m);
    b.z = __expf(b.z - m); b.w = __expf(b.w - m);

    float s = a.x + a.y + a.z + a.w + b.x + b.y + b.z + b.w;
#pragma unroll
    for (int off = 32; off; off >>= 1) s += __shfl_xor(s, off);
    if ((threadIdx.x & 63) == 0) red[wid] = s;
    __syncthreads();
    s = red[0] + red[1] + red[2] + red[3];
    float inv = 1.0f / s;

    ushort* qp = P + row * 2048 + threadIdx.x * 8;
    ushort4 oA, oB;
    oA.x = f2h(a.x * inv); oA.y = f2h(a.y * inv);
    oA.z = f2h(a.z * inv); oA.w = f2h(a.w * inv);
    oB.x = f2h(b.x * inv); oB.y = f2h(b.y * inv);
    oB.z = f2h(b.z * inv); oB.w = f2h(b.w * inv);
    ((ushort4*)qp)[0] = oA;
    ((ushort4*)qp)[1] = oB;
}

// ===========================================================================
// Fallback fp32 path (used only if ws_size is too small)
// ===========================================================================
#define BMF 128
#define BNF 128
#define BKF 16

template<bool NT, int MODE>
__global__ __launch_bounds__(256) void gemm_f32(
    const float* __restrict__ A, const float* __restrict__ A2, int Ksplit,
    const float* __restrict__ Bm, const float* __restrict__ bias,
    float* __restrict__ C,
    long lda, long ldb, long ldc, int K,
    long sAb, long sBb, long sCb)
{
    __shared__ float As[BKF][BMF + 4];
    __shared__ float Bs[BKF][BNF + 4];

    const int bz = blockIdx.z;
    const float* Ab  = A + (long)bz * sAb;
    const float* A2b = A2 ? (A2 + (long)bz * sAb) : nullptr;
    const float* Bb  = Bm + (long)bz * sBb;
    float*       Cb  = C + (long)bz * sCb;

    const int m0 = blockIdx.y * BMF;
    const int n0 = blockIdx.x * BNF;
    const int t  = threadIdx.x;
    const int tx = t & 15;
    const int ty = t >> 4;

    float acc[8][8];
#pragma unroll
    for (int i = 0; i < 8; ++i)
#pragma unroll
        for (int j = 0; j < 8; ++j) acc[i][j] = 0.f;

    for (int k0 = 0; k0 < K; k0 += BKF) {
        const float* Asrc = (A2b && k0 >= Ksplit) ? (A2b - Ksplit) : Ab;
#pragma unroll
        for (int c = 0; c < 2; ++c) {
            int chunk = t + c * 256;
            int row = chunk >> 2;
            int kq  = chunk & 3;
            float4 v = *(const float4*)(Asrc + (long)(m0 + row) * lda + k0 + kq * 4);
            As[kq * 4 + 0][row] = v.x;
            As[kq * 4 + 1][row] = v.y;
            As[kq * 4 + 2][row] = v.z;
            As[kq * 4 + 3][row] = v.w;
        }
        if (NT) {
#pragma unroll
            for (int c = 0; c < 2; ++c) {
                int chunk = t + c * 256;
                int row = chunk >> 2;
                int kq  = chunk & 3;
                float4 v = *(const float4*)(Bb + (long)(n0 + row) * ldb + k0 + kq * 4);
                Bs[kq * 4 + 0][row] = v.x;
                Bs[kq * 4 + 1][row] = v.y;
                Bs[kq * 4 + 2][row] = v.z;
                Bs[kq * 4 + 3][row] = v.w;
            }
        } else {
#pragma unroll
            for (int c = 0; c < 2; ++c) {
                int chunk = t + c * 256;
                int kr = chunk >> 5;
                int vq = chunk & 31;
                float4 v = *(const float4*)(Bb + (long)(k0 + kr) * ldb + n0 + vq * 4);
                *(float4*)&Bs[kr][vq * 4] = v;
            }
        }
        __syncthreads();

#pragma unroll
        for (int k = 0; k < BKF; ++k) {
            float4 a0 = *(const float4*)&As[k][ty * 8];
            float4 a1 = *(const float4*)&As[k][ty * 8 + 4];
            float4 b0 = *(const float4*)&Bs[k][tx * 8];
            float4 b1 = *(const float4*)&Bs[k][tx * 8 + 4];
            float ar[8] = {a0.x, a0.y, a0.z, a0.w, a1.x, a1.y, a1.z, a1.w};
            float br[8] = {b0.x, b0.y, b0.z, b0.w, b1.x, b1.y, b1.z, b1.w};
#pragma unroll
            for (int i = 0; i < 8; ++i)
#pragma unroll
                for (int j = 0; j < 8; ++j)
                    acc[i][j] += ar[i] * br[j];
        }
        __syncthreads();
    }

    float brow[8];
    if (MODE >= 1) {
#pragma unroll
        for (int j = 0; j < 8; ++j) brow[j] = bias[n0 + tx * 8 + j];
    }
#pragma unroll
    for (int i = 0; i < 8; ++i) {
        long row = m0 + ty * 8 + i;
        float v[8];
#pragma unroll
        for (int j = 0; j < 8; ++j) {
            float x = acc[i][j];
            if (MODE >= 1) x += brow[j];
            if (MODE == 2) x = tanhf(x);
            v[j] = x;
        }
        float4* dst = (float4*)&Cb[row * ldc + n0 + tx * 8];
        dst[0] = make_float4(v[0], v[1], v[2], v[3]);
        dst[1] = make_float4(v[4], v[5], v[6], v[7]);
    }
}

__global__ __launch_bounds__(256) void softmax2048(float* __restrict__ S)
{
    __shared__ float red[4];
    float* p = S + (long)blockIdx.x * 2048 + threadIdx.x * 8;
    float4 a = ((float4*)p)[0];
    float4 b = ((float4*)p)[1];

    float m = fmaxf(fmaxf(fmaxf(a.x, a.y), fmaxf(a.z, a.w)),
                    fmaxf(fmaxf(b.x, b.y), fmaxf(b.z, b.w)));
#pragma unroll
    for (int off = 32; off; off >>= 1) m = fmaxf(m, __shfl_xor(m, off));
    int wid = threadIdx.x >> 6;
    if ((threadIdx.x & 63) == 0) red[wid] = m;
    __syncthreads();
    m = fmaxf(fmaxf(red[0], red[1]), fmaxf(red[2], red[3]));
    __syncthreads();

    a.x = __expf(a.x - m); a.y = __expf(a.y - m);
    a.z = __expf(a.z - m); a.w = __expf(a.w - m);
    b.x = __expf(b.x - m); b.y = __expf(b.y - m);
    b.z = __expf(b.z - m); b.w = __expf(b.w - m);

    float s = a.x + a.y + a.z + a.w + b.x + b.y + b.z + b.w;
#pragma unroll
    for (int off = 32; off; off >>= 1) s += __shfl_xor(s, off);
    if ((threadIdx.x & 63) == 0) red[wid] = s;
    __syncthreads();
    s = red[0] + red[1] + red[2] + red[3];
    float inv = 1.0f / s;

    a.x *= inv; a.y *= inv; a.z *= inv; a.w *= inv;
    b.x *= inv; b.y *= inv; b.z *= inv; b.w *= inv;
    ((float4*)p)[0] = a;
    ((float4*)p)[1] = b;
}

// ===========================================================================
extern "C" void kernel_launch(void* const* d_in, const int* in_sizes, int n_in,
                              void* d_out, int out_size, void* d_ws, size_t ws_size,
                              hipStream_t stream)
{
    const float* query  = (const float*)d_in[0];
    const float* values = (const float*)d_in[1];
    const float* W1     = (const float*)d_in[2];
    const float* b1     = (const float*)d_in[3];
    const float* W2     = (const float*)d_in[4];
    const float* b2     = (const float*)d_in[5];
    float* out = (float*)d_out;

    const int Bc = 32, QL = 512, SL = 2048, D = 1024, F = 2048;
    const long R = (long)QL * Bc;   // 16384

    char* p = (char*)d_ws;
    auto take = [&](size_t bytes) -> char* {
        char* r = p;
        p += (bytes + 255) & ~(size_t)255;
        return r;
    };

    ushort* q_hi  = (ushort*)take((size_t)R * D * 2);    // bf16 (K1, K5)
    ushort* q_lo  = (ushort*)take((size_t)R * D * 2);    // bf16 (K1)
    ushort* w1_hi = (ushort*)take((size_t)D * D * 2);    // bf16 pair (K1)
    ushort* w1_lo = (ushort*)take((size_t)D * D * 2);
    ushort* w2_hi = (ushort*)take((size_t)D * F * 2);    // bf16 single (K5)
    ushort* qr_h  = (ushort*)take((size_t)R * D * 2);    // fp16 pair (K2 A)
    ushort* qr_l  = (ushort*)take((size_t)R * D * 2);
    ushort* at_hi = (ushort*)take((size_t)R * D * 2);    // bf16 (K5)
    size_t fixedBytes = (size_t)(p - (char*)d_ws);

    // per batch: v16 fp16 (2MB) + vT fp16 (2MB) + scores f32 (4MB) + P fp16 (2MB)
    const size_t perBatch = (size_t)SL * D * 2 * 2 + (size_t)QL * SL * 4 + (size_t)QL * SL * 2 + 2048;
    long availB = (long)ws_size - (long)fixedBytes;
    int g = availB > 0 ? (int)(availB / (long)perBatch) : 0;
    if (g > 32) g = 32;

    if (g >= 1) {
        // ----------------------- fast MFMA path ----------------------------
        ushort* v16    = (ushort*)take((size_t)SL * D * 2 * g);
        ushort* vT     = (ushort*)take((size_t)SL * D * 2 * g);
        float*  scores = (float*) take((size_t)QL * SL * 4 * g);
        ushort* P      = (ushort*)take((size_t)QL * SL * 2 * g);

        split3_k<<<2048, 256, 0, stream>>>(
            query, q_hi, q_lo, R * D / 4,
            W1, w1_hi, w1_lo, (long)D * D / 4,
            W2, w2_hi, nullptr, (long)D * F / 4);

        // K1: qr = query.W1^T + b1 (bf16 3-term) -> fp16 pair out
        gemm8p<2, false, true><<<dim3(D / 256, R / 256, 1), 512, 0, stream>>>(
            q_hi, q_hi, q_lo, w1_hi, w1_lo, w1_hi,
            D, D, 16, 3, b1,
            nullptr, qr_h, qr_l,
            D, 0, 0, 0);

        for (int b0 = 0; b0 < Bc; b0 += g) {
            int gc = (Bc - b0 < g) ? (Bc - b0) : g;

            values_conv_k<<<dim3(SL / 64, D / 64, gc), 256, 0, stream>>>(
                values, v16, vT, b0, gc);

            // K2: scores = (qr_h + qr_l) . v16  (fp16 2-term) -> f32
            gemm8p<0, true, false><<<dim3(SL / 256, QL / 256, gc), 512, 0, stream>>>(
                qr_h + (size_t)b0 * D, qr_l + (size_t)b0 * D, qr_h + (size_t)b0 * D,
                v16, v16, v16,
                (long)Bc * D, (long)gc * D, 16, 2, nullptr,
                scores, nullptr, nullptr,
                SL, D, D, (long)QL * SL);

            softmax2048b_k<<<gc * QL, 256, 0, stream>>>(scores, P);

            // K4: att = P . vT  (fp16 1-term, K=2048) -> bf16 hi out
            gemm8p<2, true, false><<<dim3(D / 256, QL / 256, gc), 512, 0, stream>>>(
                P, P, P, vT, vT, vT,
                SL, SL, 32, 1, nullptr,
                nullptr, at_hi + (size_t)b0 * D, nullptr,
                (long)Bc * D, (long)QL * SL, (long)D * SL, D);
        }

        // K5: out = tanh([att | query] . W2^T + b2)  (bf16 1-term, 2 K-segments)
        gemm8p<3, false, false><<<dim3(D / 256, R / 256, 1), 512, 0, stream>>>(
            at_hi, q_hi, q_hi, w2_hi, w2_hi + 1024, w2_hi,
            D, F, 16, 2, b2,
            out, nullptr, nullptr,
            D, 0, 0, 0);
        return;
    }

    // ----------------------- fp32 fallback ---------------------------------
    float* qr = (float*)d_ws;
    size_t qrBytes = (size_t)R * D * sizeof(float);
    float* sc = (float*)((char*)d_ws + qrBytes);
    size_t scPerB = (size_t)QL * SL * sizeof(float);

    int grp = 32;
    if (ws_size < qrBytes + 32 * scPerB) {
        size_t avail = ws_size > qrBytes ? ws_size - qrBytes : 0;
        grp = (int)(avail / scPerB);
        if (grp < 1)  grp = 1;
        if (grp > 32) grp = 32;
    }

    {
        dim3 gd(D / BNF, R / BMF, 1);
        gemm_f32<true, 1><<<gd, 256, 0, stream>>>(
            query, nullptr, 1 << 30, W1, b1, qr,
            D, D, D, D, 0, 0, 0);
    }
    for (int b0 = 0; b0 < Bc; b0 += grp) {
        int gg = (Bc - b0 < grp) ? (Bc - b0) : grp;
        {
            dim3 gd(SL / BNF, QL / BMF, gg);
            gemm_f32<true, 0><<<gd, 256, 0, stream>>>(
                qr + (size_t)b0 * D, nullptr, 1 << 30,
                values + (size_t)b0 * D, nullptr, sc,
                (long)Bc * D, (long)Bc * D, SL, D,
                D, D, (long)QL * SL);
        }
        softmax2048<<<gg * QL, 256, 0, stream>>>(sc);
        {
            dim3 gd(D / BNF, QL / BMF, gg);
            gemm_f32<false, 0><<<gd, 256, 0, stream>>>(
                sc, nullptr, 1 << 30,
                values + (size_t)b0 * D, nullptr, qr + (size_t)b0 * D,
                SL, (long)Bc * D, (long)Bc * D, SL,
                (long)QL * SL, D, D);
        }
    }
    {
        dim3 gd(D / BNF, R / BMF, 1);
        gemm_f32<true, 2><<<gd, 256, 0, stream>>>(
            qr, query, D, W2, b2, out,
            D, 2048, D, 2048, 0, 0, 0);
    }
}

// Round 11
// 544.053 us; speedup vs baseline: 1.1885x; 1.0632x over previous
//
#include <hip/hip_runtime.h>
#include <hip/hip_bf16.h>

// GlobalAttention: Q_LEN=512, SRC_LEN=2048, B=32, D=1024, F=2048
// Round 11: all-fp16 pipeline (schedule frozen at round-9 2-phase):
//   K1: qr = (q_h + q_l).W1_16 + b1   fp16 2-term (was bf16 3-term) -> fp16 pair
//   K2: scores = (qr_h + qr_l).v16    fp16 2-term, f32 out
//   SM: softmax -> P fp16
//   K4: att = P . vT                  fp16 1-term -> fp16-hi out
//   K5: tanh([att|q_h].W2_16 + b2)    fp16 1-term, 2 K-segments
// Executed GEMM work 378 -> 343 GF; w1_lo buffer/split dropped.
// Error budget: W1-fp16 adds score err ~5.2e-3 (= v16's) -> absmax ~0.013.

typedef __attribute__((ext_vector_type(8))) short    bf16x8;
typedef __attribute__((ext_vector_type(8))) _Float16 f16x8;
typedef __attribute__((ext_vector_type(4))) float    f32x4;

__device__ __forceinline__ ushort f2h(float x) {
    _Float16 h = (_Float16)x;
    return __builtin_bit_cast(ushort, h);
}
__device__ __forceinline__ float h2f(ushort u) {
    return (float)__builtin_bit_cast(_Float16, u);
}
__device__ __forceinline__ void async16(const ushort* g, ushort* l) {
    __builtin_amdgcn_global_load_lds(
        (const __attribute__((address_space(1))) unsigned int*)g,
        (__attribute__((address_space(3))) unsigned int*)l, 16, 0, 0);
}

__device__ __forceinline__ f32x4 mmop(bf16x8 a, bf16x8 b, f32x4 c) {
    return __builtin_amdgcn_mfma_f32_16x16x32_f16(
        __builtin_bit_cast(f16x8, a), __builtin_bit_cast(f16x8, b), c, 0, 0, 0);
}

#define WAITVM(N) asm volatile("s_waitcnt vmcnt(" #N ")" ::: "memory")
#define BARF() do { __builtin_amdgcn_sched_barrier(0);          \
                    __builtin_amdgcn_s_barrier();               \
                    __builtin_amdgcn_sched_barrier(0);          \
                    asm volatile("" ::: "memory"); } while (0)

// read A-quadrant QM (4 m-frags x 2 k-windows) into av
#define RD_A(QM)                                                              \
  _Pragma("unroll") for (int mi = 0; mi < 4; ++mi)                            \
  _Pragma("unroll") for (int w = 0; w < 2; ++w) {                             \
    const int row_ = (QM)*128 + wmg*64 + mi*16 + lr;                          \
    av[mi][w] = *(const bf16x8*)(bufc + row_*64 + (((w*4+lg)^(lr&7))*8));     \
  }
// read B-quadrant QN (2 n-frags x 2 k-windows) into DST
#define RD_B(QN, DST)                                                         \
  _Pragma("unroll") for (int nj = 0; nj < 2; ++nj)                            \
  _Pragma("unroll") for (int w = 0; w < 2; ++w) {                             \
    const int row_ = (QN)*128 + wnd*32 + nj*16 + lr;                          \
    DST[nj][w] = *(const bf16x8*)(bufc + 16384 + row_*64 + (((w*4+lg)^(lr&7))*8)); \
  }
#define MM(QM, QN, BSRC)                                                      \
  _Pragma("unroll") for (int w = 0; w < 2; ++w)                               \
  _Pragma("unroll") for (int mi = 0; mi < 4; ++mi)                            \
  _Pragma("unroll") for (int nj = 0; nj < 2; ++nj)                            \
    acc[(QM)*4+mi][(QN)*2+nj] = mmop(                                         \
        av[mi][w], BSRC[nj][w], acc[(QM)*4+mi][(QN)*2+nj]);

// ---------------------------------------------------------------------------
// gemm8p: C[m,n] = sum_{seg} sum_k A_s[m*lda+k]*B_s[n*ldb+k]  (NT, K-segments)
// 256x256 tile, BK=64, 512 thr (8 waves: wmg=wid>>2, wnd=wid&3), all fp16.
// Round-9 2-phase schedule per K-tile:
//   phA: vmcnt(2) -> bar -> stage A0',B0' -> RD A0,B0,B1 -> 32 MFMA
//   phB: vmcnt(4) -> bar -> stage B1',A1' -> RD A1      -> 32 MFMA
// 8-slot XOR swizzle c16^(row&7) both sides (0 conflicts, 7 rounds).
// OUTMODE: 0=f32, 2=fp16 hi (+lo if non-null)(+bias if non-null), 3=tanh(x+bias)
// ---------------------------------------------------------------------------
template<int OUTMODE>
__global__ __launch_bounds__(512, 2) void gemm8p(
    const ushort* __restrict__ A0s, const ushort* __restrict__ A1s, const ushort* __restrict__ A2s,
    const ushort* __restrict__ B0s, const ushort* __restrict__ B1s, const ushort* __restrict__ B2s,
    long lda, long ldb, int tps, int nseg,
    const float* __restrict__ bias,
    float* __restrict__ Cf, ushort* __restrict__ Chi, ushort* __restrict__ Clo,
    long ldc, long sAb, long sBb, long sCb)
{
    __shared__ ushort lds[2][32768];   // 2 x 64 KiB

    const int t   = threadIdx.x;
    const int l   = t & 63;
    const int wid = t >> 6;
    const int lr  = l & 15;
    const int lg  = l >> 4;
    const int wmg = wid >> 2;   // 0..1  (m position)
    const int wnd = wid & 3;    // 0..3  (n position)

    // XCD-aware bijective block swizzle (all grids have nwg % 8 == 0)
    const int gx = gridDim.x, gy = gridDim.y;
    const int nwg = gx * gy * gridDim.z;
    int w0 = ((int)blockIdx.z * gy + (int)blockIdx.y) * gx + (int)blockIdx.x;
    w0 = (w0 & 7) * (nwg >> 3) + (w0 >> 3);
    const int bx = w0 % gx;
    const int by = (w0 / gx) % gy;
    const int bz = w0 / (gx * gy);

    const long m0 = (long)by * 256;
    const long n0 = (long)bx * 256;

    const ushort* Asg[3] = { A0s + (long)bz * sAb, A1s + (long)bz * sAb, A2s + (long)bz * sAb };
    const ushort* Bsg[3] = { B0s + (long)bz * sBb, B1s + (long)bz * sBb, B2s + (long)bz * sBb };
    const int NTt = nseg * tps;

    // staging: half-tile = 128 rows x 64 k = 2 loads/thread; dest linear,
    // source slot pre-swizzled (t&7)^(rA&7) (row+64 preserves &7).
    const int  rA = t >> 3;
    const long cS = (long)((t & 7) ^ (rA & 7)) * 8;

    auto STAGE = [&](int kt1, bool isB, int half, int destoff) {
        int s2 = (kt1 >= tps) + (kt1 >= 2 * tps);
        long ko = (long)(kt1 - s2 * tps) * 64;
        const ushort* base = isB ? Bsg[s2] : Asg[s2];
        long ld = isB ? ldb : lda;
        long rb = isB ? n0 : m0;
        const ushort* src = base + (rb + half * 128 + rA) * ld + ko + cS;
        ushort* d = &lds[kt1 & 1][destoff + t * 8];
        async16(src, d);
        async16(src + 64 * ld, d + 4096);
    };

    const f32x4 zero = {0.f, 0.f, 0.f, 0.f};
    f32x4 acc[8][4];
#pragma unroll
    for (int i = 0; i < 8; ++i)
#pragma unroll
        for (int j = 0; j < 4; ++j) acc[i][j] = zero;

    // prologue: tile 0, stage order A0,B0,B1,A1 (matches consume accounting)
    STAGE(0, false, 0, 0);
    STAGE(0, true,  0, 16384);
    STAGE(0, true,  1, 24576);
    STAGE(0, false, 1, 8192);

    bf16x8 av[4][2], bv0[2][2], bv1[2][2];

    for (int kt = 0; kt < NTt - 1; ++kt) {
        const ushort* bufc = &lds[kt & 1][0];
        // phase A: quadrants (0,0),(0,1). Needs A0,B0,B1 -> vmcnt(2).
        WAITVM(2); BARF();
        STAGE(kt + 1, false, 0, 0);
        STAGE(kt + 1, true,  0, 16384);
        RD_A(0); RD_B(0, bv0); RD_B(1, bv1);
        __builtin_amdgcn_s_setprio(1);
        MM(0, 0, bv0); MM(0, 1, bv1);
        __builtin_amdgcn_s_setprio(0);
        // phase B: quadrants (1,0),(1,1). Needs A1 -> vmcnt(4).
        WAITVM(4); BARF();
        STAGE(kt + 1, true,  1, 24576);
        STAGE(kt + 1, false, 1, 8192);
        RD_A(1);
        __builtin_amdgcn_s_setprio(1);
        MM(1, 0, bv0); MM(1, 1, bv1);
        __builtin_amdgcn_s_setprio(0);
    }
    {   // last tile: no staging; graduated drain
        const ushort* bufc = &lds[(NTt - 1) & 1][0];
        WAITVM(2); BARF();
        RD_A(0); RD_B(0, bv0); RD_B(1, bv1);
        __builtin_amdgcn_s_setprio(1);
        MM(0, 0, bv0); MM(0, 1, bv1);
        __builtin_amdgcn_s_setprio(0);
        WAITVM(0); BARF();
        RD_A(1);
        __builtin_amdgcn_s_setprio(1);
        MM(1, 0, bv0); MM(1, 1, bv1);
        __builtin_amdgcn_s_setprio(0);
    }

    // epilogue: 16x16 C/D mapping col = l&15, row = (l>>4)*4 + reg
    float*  Cfb = Cf  ? (Cf  + (long)bz * sCb) : nullptr;
    ushort* Chb = Chi ? (Chi + (long)bz * sCb) : nullptr;
    ushort* Clb = Clo ? (Clo + (long)bz * sCb) : nullptr;
#pragma unroll
    for (int qn = 0; qn < 2; ++qn)
#pragma unroll
    for (int nj = 0; nj < 2; ++nj) {
        long n = n0 + qn * 128 + wnd * 32 + nj * 16 + lr;
        float bvs = 0.f;
        if (OUTMODE == 3) bvs = bias[n];
        if (OUTMODE == 2) { if (bias) bvs = bias[n]; }
#pragma unroll
        for (int qm = 0; qm < 2; ++qm)
#pragma unroll
        for (int mi = 0; mi < 4; ++mi) {
            long mb = m0 + qm * 128 + wmg * 64 + mi * 16 + lg * 4;
#pragma unroll
            for (int r = 0; r < 4; ++r) {
                float x = acc[qm * 4 + mi][qn * 2 + nj][r] + bvs;
                long idx = (mb + r) * ldc + n;
                if (OUTMODE == 3) {
                    Cfb[idx] = tanhf(x);
                } else if (OUTMODE == 2) {
                    ushort h = f2h(x);
                    Chb[idx] = h;
                    if (Clb) Clb[idx] = f2h(x - h2f(h));
                } else {
                    Cfb[idx] = x;
                }
            }
        }
    }
}

// ---------------------------------------------------------------------------
// Merged elementwise f32 -> (hi, lo) fp16 pair over three arrays (lo nullable)
// ---------------------------------------------------------------------------
__global__ __launch_bounds__(256) void split3h_k(
    const float* __restrict__ a0, ushort* __restrict__ h0, ushort* __restrict__ l0, long n0,
    const float* __restrict__ a1, ushort* __restrict__ h1, ushort* __restrict__ l1, long n1,
    const float* __restrict__ a2, ushort* __restrict__ h2, ushort* __restrict__ l2, long n2)
{
    long i = (long)blockIdx.x * 256 + threadIdx.x;
    const long stride = (long)gridDim.x * 256;
    const long tot = n0 + n1 + n2;
    for (; i < tot; i += stride) {
        const float* src; ushort* hh; ushort* ll; long j = i;
        if (j < n0)           { src = a0; hh = h0; ll = l0; }
        else if (j < n0 + n1) { j -= n0; src = a1; hh = h1; ll = l1; }
        else                  { j -= n0 + n1; src = a2; hh = h2; ll = l2; }
        float4 x = ((const float4*)src)[j];
        ushort4 h;
        h.x = f2h(x.x); h.y = f2h(x.y); h.z = f2h(x.z); h.w = f2h(x.w);
        ((ushort4*)hh)[j] = h;
        if (ll) {
            ushort4 lw;
            lw.x = f2h(x.x - h2f(h.x));
            lw.y = f2h(x.y - h2f(h.y));
            lw.z = f2h(x.z - h2f(h.z));
            lw.w = f2h(x.w - h2f(h.w));
            ((ushort4*)ll)[j] = lw;
        }
    }
}

// ---------------------------------------------------------------------------
// values [2048][32][1024] f32 -> per batch-group:
//   v16 [(s*gc+bi)][1024] fp16   (K2 B-operand, NT)
//   vT  [bi][1024][2048]  fp16   (K4 B-operand, NT)
// ---------------------------------------------------------------------------
__global__ __launch_bounds__(256) void values_conv_k(
    const float* __restrict__ values,
    ushort* __restrict__ v16, ushort* __restrict__ vT,
    int b0, int gc)
{
    __shared__ float tile[64][65];
    const int t  = threadIdx.x;
    const int s0 = blockIdx.x * 64;
    const int v0 = blockIdx.y * 64;
    const int bi = blockIdx.z;
    const int b  = b0 + bi;
#pragma unroll
    for (int i = 0; i < 4; ++i) {
        int c = t + i * 256;
        int r = c >> 4;
        int qq = c & 15;
        float4 x = *(const float4*)(values + ((long)(s0 + r) * 32 + b) * 1024 + v0 + qq * 4);
        ushort4 h;
        h.x = f2h(x.x); h.y = f2h(x.y); h.z = f2h(x.z); h.w = f2h(x.w);
        long rowoff = ((long)(s0 + r) * gc + bi) * 1024 + v0 + qq * 4;
        *(ushort4*)(v16 + rowoff) = h;
        tile[r][qq * 4 + 0] = x.x;
        tile[r][qq * 4 + 1] = x.y;
        tile[r][qq * 4 + 2] = x.z;
        tile[r][qq * 4 + 3] = x.w;
    }
    __syncthreads();
    const int vr = t >> 2;
    const int ss = (t & 3) * 16;
    ushort* dst = vT + ((long)bi * 1024 + v0 + vr) * 2048 + s0 + ss;
#pragma unroll
    for (int j = 0; j < 4; ++j) {
        ushort4 o;
        o.x = f2h(tile[ss + j * 4 + 0][vr]);
        o.y = f2h(tile[ss + j * 4 + 1][vr]);
        o.z = f2h(tile[ss + j * 4 + 2][vr]);
        o.w = f2h(tile[ss + j * 4 + 3][vr]);
        *(ushort4*)(dst + j * 4) = o;
    }
}

// softmax over 2048-rows, f32 in -> fp16 P out. One 256-thread block per row.
__global__ __launch_bounds__(256) void softmax2048b_k(
    const float* __restrict__ S, ushort* __restrict__ P)
{
    __shared__ float red[4];
    const long row = blockIdx.x;
    const float* p = S + row * 2048 + threadIdx.x * 8;
    float4 a = ((const float4*)p)[0];
    float4 b = ((const float4*)p)[1];

    float m = fmaxf(fmaxf(fmaxf(a.x, a.y), fmaxf(a.z, a.w)),
                    fmaxf(fmaxf(b.x, b.y), fmaxf(b.z, b.w)));
#pragma unroll
    for (int off = 32; off; off >>= 1) m = fmaxf(m, __shfl_xor(m, off));
    int wid = threadIdx.x >> 6;
    if ((threadIdx.x & 63) == 0) red[wid] = m;
    __syncthreads();
    m = fmaxf(fmaxf(red[0], red[1]), fmaxf(red[2], red[3]));
    __syncthreads();

    a.x = __expf(a.x - m); a.y = __expf(a.y - m);
    a.z = __expf(a.z - m); a.w = __expf(a.w - m);
    b.x = __expf(b.x - m); b.y = __expf(b.y - m);
    b.z = __expf(b.z - m); b.w = __expf(b.w - m);

    float s = a.x + a.y + a.z + a.w + b.x + b.y + b.z + b.w;
#pragma unroll
    for (int off = 32; off; off >>= 1) s += __shfl_xor(s, off);
    if ((threadIdx.x & 63) == 0) red[wid] = s;
    __syncthreads();
    s = red[0] + red[1] + red[2] + red[3];
    float inv = 1.0f / s;

    ushort* qp = P + row * 2048 + threadIdx.x * 8;
    ushort4 oA, oB;
    oA.x = f2h(a.x * inv); oA.y = f2h(a.y * inv);
    oA.z = f2h(a.z * inv); oA.w = f2h(a.w * inv);
    oB.x = f2h(b.x * inv); oB.y = f2h(b.y * inv);
    oB.z = f2h(b.z * inv); oB.w = f2h(b.w * inv);
    ((ushort4*)qp)[0] = oA;
    ((ushort4*)qp)[1] = oB;
}

// ===========================================================================
// Fallback fp32 path (used only if ws_size is too small)
// ===========================================================================
#define BMF 128
#define BNF 128
#define BKF 16

template<bool NT, int MODE>
__global__ __launch_bounds__(256) void gemm_f32(
    const float* __restrict__ A, const float* __restrict__ A2, int Ksplit,
    const float* __restrict__ Bm, const float* __restrict__ bias,
    float* __restrict__ C,
    long lda, long ldb, long ldc, int K,
    long sAb, long sBb, long sCb)
{
    __shared__ float As[BKF][BMF + 4];
    __shared__ float Bs[BKF][BNF + 4];

    const int bz = blockIdx.z;
    const float* Ab  = A + (long)bz * sAb;
    const float* A2b = A2 ? (A2 + (long)bz * sAb) : nullptr;
    const float* Bb  = Bm + (long)bz * sBb;
    float*       Cb  = C + (long)bz * sCb;

    const int m0 = blockIdx.y * BMF;
    const int n0 = blockIdx.x * BNF;
    const int t  = threadIdx.x;
    const int tx = t & 15;
    const int ty = t >> 4;

    float acc[8][8];
#pragma unroll
    for (int i = 0; i < 8; ++i)
#pragma unroll
        for (int j = 0; j < 8; ++j) acc[i][j] = 0.f;

    for (int k0 = 0; k0 < K; k0 += BKF) {
        const float* Asrc = (A2b && k0 >= Ksplit) ? (A2b - Ksplit) : Ab;
#pragma unroll
        for (int c = 0; c < 2; ++c) {
            int chunk = t + c * 256;
            int row = chunk >> 2;
            int kq  = chunk & 3;
            float4 v = *(const float4*)(Asrc + (long)(m0 + row) * lda + k0 + kq * 4);
            As[kq * 4 + 0][row] = v.x;
            As[kq * 4 + 1][row] = v.y;
            As[kq * 4 + 2][row] = v.z;
            As[kq * 4 + 3][row] = v.w;
        }
        if (NT) {
#pragma unroll
            for (int c = 0; c < 2; ++c) {
                int chunk = t + c * 256;
                int row = chunk >> 2;
                int kq  = chunk & 3;
                float4 v = *(const float4*)(Bb + (long)(n0 + row) * ldb + k0 + kq * 4);
                Bs[kq * 4 + 0][row] = v.x;
                Bs[kq * 4 + 1][row] = v.y;
                Bs[kq * 4 + 2][row] = v.z;
                Bs[kq * 4 + 3][row] = v.w;
            }
        } else {
#pragma unroll
            for (int c = 0; c < 2; ++c) {
                int chunk = t + c * 256;
                int kr = chunk >> 5;
                int vq = chunk & 31;
                float4 v = *(const float4*)(Bb + (long)(k0 + kr) * ldb + n0 + vq * 4);
                *(float4*)&Bs[kr][vq * 4] = v;
            }
        }
        __syncthreads();

#pragma unroll
        for (int k = 0; k < BKF; ++k) {
            float4 a0 = *(const float4*)&As[k][ty * 8];
            float4 a1 = *(const float4*)&As[k][ty * 8 + 4];
            float4 b0 = *(const float4*)&Bs[k][tx * 8];
            float4 b1 = *(const float4*)&Bs[k][tx * 8 + 4];
            float ar[8] = {a0.x, a0.y, a0.z, a0.w, a1.x, a1.y, a1.z, a1.w};
            float br[8] = {b0.x, b0.y, b0.z, b0.w, b1.x, b1.y, b1.z, b1.w};
#pragma unroll
            for (int i = 0; i < 8; ++i)
#pragma unroll
                for (int j = 0; j < 8; ++j)
                    acc[i][j] += ar[i] * br[j];
        }
        __syncthreads();
    }

    float brow[8];
    if (MODE >= 1) {
#pragma unroll
        for (int j = 0; j < 8; ++j) brow[j] = bias[n0 + tx * 8 + j];
    }
#pragma unroll
    for (int i = 0; i < 8; ++i) {
        long row = m0 + ty * 8 + i;
        float v[8];
#pragma unroll
        for (int j = 0; j < 8; ++j) {
            float x = acc[i][j];
            if (MODE >= 1) x += brow[j];
            if (MODE == 2) x = tanhf(x);
            v[j] = x;
        }
        float4* dst = (float4*)&Cb[row * ldc + n0 + tx * 8];
        dst[0] = make_float4(v[0], v[1], v[2], v[3]);
        dst[1] = make_float4(v[4], v[5], v[6], v[7]);
    }
}

__global__ __launch_bounds__(256) void softmax2048(float* __restrict__ S)
{
    __shared__ float red[4];
    float* p = S + (long)blockIdx.x * 2048 + threadIdx.x * 8;
    float4 a = ((float4*)p)[0];
    float4 b = ((float4*)p)[1];

    float m = fmaxf(fmaxf(fmaxf(a.x, a.y), fmaxf(a.z, a.w)),
                    fmaxf(fmaxf(b.x, b.y), fmaxf(b.z, b.w)));
#pragma unroll
    for (int off = 32; off; off >>= 1) m = fmaxf(m, __shfl_xor(m, off));
    int wid = threadIdx.x >> 6;
    if ((threadIdx.x & 63) == 0) red[wid] = m;
    __syncthreads();
    m = fmaxf(fmaxf(red[0], red[1]), fmaxf(red[2], red[3]));
    __syncthreads();

    a.x = __expf(a.x - m); a.y = __expf(a.y - m);
    a.z = __expf(a.z - m); a.w = __expf(a.w - m);
    b.x = __expf(b.x - m); b.y = __expf(b.y - m);
    b.z = __expf(b.z - m); b.w = __expf(b.w - m);

    float s = a.x + a.y + a.z + a.w + b.x + b.y + b.z + b.w;
#pragma unroll
    for (int off = 32; off; off >>= 1) s += __shfl_xor(s, off);
    if ((threadIdx.x & 63) == 0) red[wid] = s;
    __syncthreads();
    s = red[0] + red[1] + red[2] + red[3];
    float inv = 1.0f / s;

    a.x *= inv; a.y *= inv; a.z *= inv; a.w *= inv;
    b.x *= inv; b.y *= inv; b.z *= inv; b.w *= inv;
    ((float4*)p)[0] = a;
    ((float4*)p)[1] = b;
}

// ===========================================================================
extern "C" void kernel_launch(void* const* d_in, const int* in_sizes, int n_in,
                              void* d_out, int out_size, void* d_ws, size_t ws_size,
                              hipStream_t stream)
{
    const float* query  = (const float*)d_in[0];
    const float* values = (const float*)d_in[1];
    const float* W1     = (const float*)d_in[2];
    const float* b1     = (const float*)d_in[3];
    const float* W2     = (const float*)d_in[4];
    const float* b2     = (const float*)d_in[5];
    float* out = (float*)d_out;

    const int Bc = 32, QL = 512, SL = 2048, D = 1024, F = 2048;
    const long R = (long)QL * Bc;   // 16384

    char* p = (char*)d_ws;
    auto take = [&](size_t bytes) -> char* {
        char* r = p;
        p += (bytes + 255) & ~(size_t)255;
        return r;
    };

    ushort* q_h   = (ushort*)take((size_t)R * D * 2);    // fp16 pair (K1 A, K5 A2)
    ushort* q_l   = (ushort*)take((size_t)R * D * 2);
    ushort* w1_16 = (ushort*)take((size_t)D * D * 2);    // fp16 single (K1 B)
    ushort* w2_16 = (ushort*)take((size_t)D * F * 2);    // fp16 single (K5 B)
    ushort* qr_h  = (ushort*)take((size_t)R * D * 2);    // fp16 pair (K2 A)
    ushort* qr_l  = (ushort*)take((size_t)R * D * 2);
    ushort* at_16 = (ushort*)take((size_t)R * D * 2);    // fp16 (K5 A)
    size_t fixedBytes = (size_t)(p - (char*)d_ws);

    // per batch: v16 fp16 (2MB) + vT fp16 (2MB) + scores f32 (4MB) + P fp16 (2MB)
    const size_t perBatch = (size_t)SL * D * 2 * 2 + (size_t)QL * SL * 4 + (size_t)QL * SL * 2 + 2048;
    long availB = (long)ws_size - (long)fixedBytes;
    int g = availB > 0 ? (int)(availB / (long)perBatch) : 0;
    if (g > 32) g = 32;

    if (g >= 1) {
        // ----------------------- fast fp16 MFMA path -----------------------
        ushort* v16    = (ushort*)take((size_t)SL * D * 2 * g);
        ushort* vT     = (ushort*)take((size_t)SL * D * 2 * g);
        float*  scores = (float*) take((size_t)QL * SL * 4 * g);
        ushort* P      = (ushort*)take((size_t)QL * SL * 2 * g);

        split3h_k<<<2048, 256, 0, stream>>>(
            query, q_h, q_l, R * D / 4,
            W1, w1_16, nullptr, (long)D * D / 4,
            W2, w2_16, nullptr, (long)D * F / 4);

        // K1: qr = (q_h + q_l).W1_16 + b1  (fp16 2-term) -> fp16 pair out
        gemm8p<2><<<dim3(D / 256, R / 256, 1), 512, 0, stream>>>(
            q_h, q_l, q_h, w1_16, w1_16, w1_16,
            D, D, 16, 2, b1,
            nullptr, qr_h, qr_l,
            D, 0, 0, 0);

        for (int b0 = 0; b0 < Bc; b0 += g) {
            int gc = (Bc - b0 < g) ? (Bc - b0) : g;

            values_conv_k<<<dim3(SL / 64, D / 64, gc), 256, 0, stream>>>(
                values, v16, vT, b0, gc);

            // K2: scores = (qr_h + qr_l) . v16  (fp16 2-term) -> f32
            gemm8p<0><<<dim3(SL / 256, QL / 256, gc), 512, 0, stream>>>(
                qr_h + (size_t)b0 * D, qr_l + (size_t)b0 * D, qr_h + (size_t)b0 * D,
                v16, v16, v16,
                (long)Bc * D, (long)gc * D, 16, 2, nullptr,
                scores, nullptr, nullptr,
                SL, D, D, (long)QL * SL);

            softmax2048b_k<<<gc * QL, 256, 0, stream>>>(scores, P);

            // K4: att = P . vT  (fp16 1-term, K=2048) -> fp16 hi out
            gemm8p<2><<<dim3(D / 256, QL / 256, gc), 512, 0, stream>>>(
                P, P, P, vT, vT, vT,
                SL, SL, 32, 1, nullptr,
                nullptr, at_16 + (size_t)b0 * D, nullptr,
                (long)Bc * D, (long)QL * SL, (long)D * SL, D);
        }

        // K5: out = tanh([att | q_h] . W2_16 + b2)  (fp16 1-term, 2 K-segments)
        gemm8p<3><<<dim3(D / 256, R / 256, 1), 512, 0, stream>>>(
            at_16, q_h, q_h, w2_16, w2_16 + 1024, w2_16,
            D, F, 16, 2, b2,
            out, nullptr, nullptr,
            D, 0, 0, 0);
        return;
    }

    // ----------------------- fp32 fallback ---------------------------------
    float* qr = (float*)d_ws;
    size_t qrBytes = (size_t)R * D * sizeof(float);
    float* sc = (float*)((char*)d_ws + qrBytes);
    size_t scPerB = (size_t)QL * SL * sizeof(float);

    int grp = 32;
    if (ws_size < qrBytes + 32 * scPerB) {
        size_t avail = ws_size > qrBytes ? ws_size - qrBytes : 0;
        grp = (int)(avail / scPerB);
        if (grp < 1)  grp = 1;
        if (grp > 32) grp = 32;
    }

    {
        dim3 gd(D / BNF, R / BMF, 1);
        gemm_f32<true, 1><<<gd, 256, 0, stream>>>(
            query, nullptr, 1 << 30, W1, b1, qr,
            D, D, D, D, 0, 0, 0);
    }
    for (int b0 = 0; b0 < Bc; b0 += grp) {
        int gg = (Bc - b0 < grp) ? (Bc - b0) : grp;
        {
            dim3 gd(SL / BNF, QL / BMF, gg);
            gemm_f32<true, 0><<<gd, 256, 0, stream>>>(
                qr + (size_t)b0 * D, nullptr, 1 << 30,
                values + (size_t)b0 * D, nullptr, sc,
                (long)Bc * D, (long)Bc * D, SL, D,
                D, D, (long)QL * SL);
        }
        softmax2048<<<gg * QL, 256, 0, stream>>>(sc);
        {
            dim3 gd(D / BNF, QL / BMF, gg);
            gemm_f32<false, 0><<<gd, 256, 0, stream>>>(
                sc, nullptr, 1 << 30,
                values + (size_t)b0 * D, nullptr, qr + (size_t)b0 * D,
                SL, (long)Bc * D, (long)Bc * D, SL,
                (long)QL * SL, D, D);
        }
    }
    {
        dim3 gd(D / BNF, R / BMF, 1);
        gemm_f32<true, 2><<<gd, 256, 0, stream>>>(
            qr, query, D, W2, b2, out,
            D, 2048, D, 2048, 0, 0, 0);
    }
}